// Round 8
// baseline (37.836 us; speedup 1.0000x reference)
//
#include <hip/hip_runtime.h>

#define NV 128     // vessels (N)
#define NB 256     // batches
#define NH 128     // hidden
#define KC 32      // K-chunk (j)
#define HSTR 40    // H LDS row stride in shorts (80 B; b128 bank-minimum)

typedef __attribute__((ext_vector_type(8))) unsigned short ushort8;
typedef __attribute__((ext_vector_type(4))) float f32x4;
typedef __attribute__((ext_vector_type(8))) __bf16 bf16x8;

__device__ __forceinline__ unsigned short f2bf(float x) {  // RNE f32->bf16
  unsigned u = __builtin_bit_cast(unsigned, x);
  return (unsigned short)((u + 0x7fffu + ((u >> 16) & 1u)) >> 16);
}
__device__ __forceinline__ float bf2f(unsigned short h) {
  return __builtin_bit_cast(float, (unsigned)h << 16);
}

// Detect byte-backed (numpy bool) vs word-backed mask: word-backed has
// byte1 == 0 everywhere.
__global__ void mask_detect_kernel(const unsigned char* __restrict__ mb,
                                   int* __restrict__ flag) {
  __shared__ int s;
  if (threadIdx.x == 0) s = 0;
  __syncthreads();
  int acc = 0;
  for (int i = threadIdx.x; i < 1024; i += blockDim.x) acc += mb[4 * i + 1];
  atomicAdd(&s, acc);
  __syncthreads();
  if (threadIdx.x == 0) *flag = (s == 0) ? 1 : 0;
}

// Block = (batch, i-half, hh-half): 64 i-rows x 64 hh cols. 4 waves, each
// wave owns 16 i-rows and the full 64-hh strip (4 MFMA tiles).
__launch_bounds__(256, 4)
__global__ void spatial_attn_mfma(const float* __restrict__ hidden,   // (N,B,H)
                                  const float* __restrict__ dist,     // (B,N,N)
                                  const float* __restrict__ brg,      // (B,N,N)
                                  const float* __restrict__ hdg,      // (B,N,N)
                                  const unsigned char* __restrict__ maskraw,
                                  const float* __restrict__ domain,   // (24,24)
                                  const int* __restrict__ flagp,
                                  float* __restrict__ out) {          // (B,N,H)
  __shared__ unsigned short thi[2][64 * HSTR];   // H^T hi, double-buffered
  __shared__ unsigned short tlo[2][64 * HSTR];   // H^T lo
  __shared__ float dom[24 * 24];
  __shared__ float maskf[NV];

  const int tid = threadIdx.x;
  const int lane = tid & 63;
  const int wv = tid >> 6;                   // wave 0..3
  const int b = blockIdx.x >> 2;             // batch
  const int ih = ((blockIdx.x >> 1) & 1) * 64;  // i-half base
  const int hb = (blockIdx.x & 1) * 64;         // hh-half base

  for (int k = tid; k < 576; k += 256) dom[k] = domain[k];
  if (tid < NV) {
    const int kind = *flagp;
    const int m = kind ? ((const int*)maskraw)[b * NV + tid]
                       : (int)maskraw[b * NV + tid];
    maskf[tid] = (m != 0) ? 1.0f : 0.0f;
  }
  __syncthreads();

  // MFMA fragment geometry (m89-verified)
  const int fm = lane & 15;
  const int j0 = (lane >> 4) * 8;
  const int arow = ih + 16 * wv + fm;        // this lane's A row (global i)
  const float mi = maskf[arow];

  // H staging map: thread -> one local hh row (0..63), one 8-j group
  const int srow = tid & 63;
  const int sj = (tid >> 6) << 3;
  const int hh_s = hb + srow;

  f32x4 acc[4];
#pragma unroll
  for (int t = 0; t < 4; ++t) acc[t] = (f32x4)0.0f;

  const float* dR = dist + ((size_t)b * NV + arow) * NV;
  const float* bR = brg + ((size_t)b * NV + arow) * NV;
  const float* gR = hdg + ((size_t)b * NV + arow) * NV;

  float hv[8];
#define STAGE_LOAD(cc)                                                        \
  {                                                                           \
    const int jb = (cc) * KC + sj;                                            \
    _Pragma("unroll") for (int k = 0; k < 8; ++k)                             \
        hv[k] = hidden[((size_t)(jb + k) * NB + b) * NH + hh_s];              \
  }
#define STAGE_WRITE(bb)                                                       \
  {                                                                           \
    ushort8 ph, pl;                                                           \
    _Pragma("unroll") for (int k = 0; k < 8; ++k) {                           \
      const unsigned short h = f2bf(hv[k]);                                   \
      ph[k] = h;                                                              \
      pl[k] = f2bf(hv[k] - bf2f(h));                                          \
    }                                                                         \
    *(ushort8*)&thi[bb][srow * HSTR + sj] = ph;                               \
    *(ushort8*)&tlo[bb][srow * HSTR + sj] = pl;                               \
  }

  STAGE_LOAD(0);
  STAGE_WRITE(0);

  for (int cs = 0; cs < 4; ++cs) {
    const int jc = cs * KC;
    const int cb = cs & 1;

    if (cs < 3) STAGE_LOAD(cs + 1);          // issue next-H loads early (T14)

    // ---- W: this lane's A-fragment, in registers (no LDS round-trip) ----
    const float4 d0 = *(const float4*)&dR[jc + j0];
    const float4 d1 = *(const float4*)&dR[jc + j0 + 4];
    const float4 b0 = *(const float4*)&bR[jc + j0];
    const float4 b1 = *(const float4*)&bR[jc + j0 + 4];
    const float4 g0 = *(const float4*)&gR[jc + j0];
    const float4 g1 = *(const float4*)&gR[jc + j0 + 4];
    const float dv[8] = {d0.x, d0.y, d0.z, d0.w, d1.x, d1.y, d1.z, d1.w};
    const float bv[8] = {b0.x, b0.y, b0.z, b0.w, b1.x, b1.y, b1.z, b1.w};
    const float gv[8] = {g0.x, g0.y, g0.z, g0.w, g1.x, g1.y, g1.z, g1.w};
    ushort8 ahi_u, alo_u;
#pragma unroll
    for (int e = 0; e < 8; ++e) {
      float w = 0.0f;
      if (mi != 0.0f && maskf[jc + j0 + e] != 0.0f) {
        // XLA rewrites /15.0 to * (1/15.0f): must bit-match bucket edges.
        const int i1 = min(23, max(0, (int)floorf(gv[e] * (1.0f / 15.0f))));
        const int i2 = min(23, max(0, (int)floorf(bv[e] * (1.0f / 15.0f))));
        const float t = dom[i1 * 24 + i2] - dv[e];
        w = fmaxf(t, 0.0f) + __logf(1.0f + __expf(-fabsf(t)));  // softplus
      }
      const unsigned short h = f2bf(w);
      ahi_u[e] = h;
      alo_u[e] = f2bf(w - bf2f(h));
    }
    const bf16x8 ahi = __builtin_bit_cast(bf16x8, ahi_u);
    const bf16x8 alo = __builtin_bit_cast(bf16x8, alo_u);

    __syncthreads();                          // buf cb ready; cb^1 free
    if (cs < 3) STAGE_WRITE(cb ^ 1);          // convert+write post-barrier

    // ---- MFMA: acc[t] += W * H (bf16 hi/lo x3), tiles hh = hb+16t ----
#pragma unroll
    for (int t = 0; t < 4; ++t) {
      const int boff = (16 * t + fm) * HSTR + j0;
      const bf16x8 bhi = __builtin_bit_cast(bf16x8, *(const ushort8*)&thi[cb][boff]);
      const bf16x8 blo = __builtin_bit_cast(bf16x8, *(const ushort8*)&tlo[cb][boff]);
      acc[t] = __builtin_amdgcn_mfma_f32_16x16x32_bf16(ahi, bhi, acc[t], 0, 0, 0);
      acc[t] = __builtin_amdgcn_mfma_f32_16x16x32_bf16(ahi, blo, acc[t], 0, 0, 0);
      acc[t] = __builtin_amdgcn_mfma_f32_16x16x32_bf16(alo, bhi, acc[t], 0, 0, 0);
    }
  }

  // ---- epilogue: fast tanh + row mask + store ----
  // C/D: col = lane&15, row = (lane>>4)*4 + reg
  float* oB = out + (size_t)b * NV * NH;
  const int rbase = ih + 16 * wv + 4 * (lane >> 4);
#pragma unroll
  for (int t = 0; t < 4; ++t) {
    const int hh = hb + 16 * t + fm;
#pragma unroll
    for (int r = 0; r < 4; ++r) {
      const int i = rbase + r;
      const float x = acc[t][r];
      const float ex = __expf(2.0f * x);      // inf-safe: ->1 / ->-1
      const float th = 1.0f - __fdividef(2.0f, ex + 1.0f);
      oB[i * NH + hh] = th * maskf[i];
    }
  }
}

extern "C" void kernel_launch(void* const* d_in, const int* in_sizes, int n_in,
                              void* d_out, int out_size, void* d_ws, size_t ws_size,
                              hipStream_t stream) {
  const float* hidden = (const float*)d_in[0];
  const float* dist = (const float*)d_in[1];
  const float* brg = (const float*)d_in[2];
  const float* hdg = (const float*)d_in[3];
  const unsigned char* mask = (const unsigned char*)d_in[4];
  const float* domain = (const float*)d_in[5];
  float* out = (float*)d_out;
  int* flag = (int*)d_ws;

  mask_detect_kernel<<<1, 256, 0, stream>>>(mask, flag);
  spatial_attn_mfma<<<NB * 4, 256, 0, stream>>>(hidden, dist, brg, hdg, mask,
                                                domain, flag, out);
}